// Round 1
// baseline (108.102 us; speedup 1.0000x reference)
//
#include <hip/hip_runtime.h>
#include <hip/hip_bf16.h>

#define IMAGE_SIZE 416
#define DECODED 64
#define NPIX (IMAGE_SIZE * IMAGE_SIZE)   // 173056
#define M_OBJ 128                        // B*N = 4*32
#define D_IN 64
#define H1 512
#define OUT2 12288                       // 3*64*64

// ---------------- Kernel 1: hid = relu(z_what @ w1 + b1) ----------------
// grid: 128 blocks (one per object row), 512 threads (one per hidden unit)
__global__ __launch_bounds__(512) void mlp1_kernel(const float* __restrict__ z_what,
                                                   const float* __restrict__ w1,
                                                   const float* __restrict__ b1,
                                                   float* __restrict__ hid) {
    const int i = blockIdx.x;
    const int h = threadIdx.x;
    const float* zr = z_what + i * D_IN;   // uniform per block -> scalar loads
    float acc = b1[h];
#pragma unroll
    for (int d = 0; d < D_IN; ++d)
        acc = fmaf(zr[d], w1[d * H1 + h], acc);
    hid[i * H1 + h] = fmaxf(acc, 0.0f);
}

// ---------------- Kernel 2: dec = sigmoid(hid @ w2 + b2) ----------------
// grid: (48, 8); block 256. Each block: 16 rows x 256 cols.
__global__ __launch_bounds__(256) void mlp2_kernel(const float* __restrict__ hid,
                                                   const float* __restrict__ w2,
                                                   const float* __restrict__ b2,
                                                   float* __restrict__ dec) {
    const int j = blockIdx.x * 256 + threadIdx.x;   // output column 0..12287
    const int i0 = blockIdx.y * 16;                 // row-tile base
    float acc[16];
#pragma unroll
    for (int r = 0; r < 16; ++r) acc[r] = 0.0f;

    const float* hrow = hid + i0 * H1;  // uniform -> s_load path
    const float* wp = w2 + j;
    for (int k = 0; k < 512; ++k) {
        float w = wp[(size_t)k * OUT2];  // coalesced across threads
#pragma unroll
        for (int r = 0; r < 16; ++r)
            acc[r] = fmaf(hrow[r * H1 + k], w, acc[r]);
    }
    const float bb = b2[j];
#pragma unroll
    for (int r = 0; r < 16; ++r) {
        float x = acc[r] + bb;
        float v = 1.0f / (1.0f + __expf(-x));
        dec[(size_t)(i0 + r) * OUT2 + j] = v;
    }
}

// ---------------- Kernel 3: per-object params (softmax weights + STN constants) ----
// obj layout per object (8 floats): tx, ty, inv_sx, inv_sy, weight, 0,0,0
__global__ __launch_bounds__(128) void wts_kernel(const float* __restrict__ z_where,
                                                  const int* __restrict__ z_present,
                                                  const float* __restrict__ z_depth,
                                                  float* __restrict__ obj) {
    const int t = threadIdx.x;       // 0..127 -> (b = t>>5, n = t&31)
    const int b = t >> 5;
    __shared__ float sd[128];
    __shared__ float se[128];

    const int pres = z_present[t];
    const float d = pres ? z_depth[t] : -1000.0f;
    sd[t] = d;
    __syncthreads();

    float m = -1e30f;
#pragma unroll
    for (int k = 0; k < 32; ++k) m = fmaxf(m, sd[(b << 5) + k]);
    const float e = expf(d - m);     // underflows to 0 for absent objects
    se[t] = e;
    __syncthreads();

    float s = 0.0f;
#pragma unroll
    for (int k = 0; k < 32; ++k) s += se[(b << 5) + k];
    const float wgt = pres ? (e / s) : 0.0f;

    const float xc = z_where[t * 4 + 0];
    const float yc = z_where[t * 4 + 1];
    const float ww = z_where[t * 4 + 2];
    const float hh = z_where[t * 4 + 3];
    float* o = obj + t * 8;
    o[0] = 2.0f * xc - 1.0f;
    o[1] = 2.0f * yc - 1.0f;
    o[2] = 1.0f / fmaxf(ww, 0.001f);
    o[3] = 1.0f / fmaxf(hh, 0.001f);
    o[4] = wgt;
    o[5] = 0.0f; o[6] = 0.0f; o[7] = 0.0f;
}

// ---------------- Kernel 4: composite --------------------------------------
// grid: (676, 4); block 256. One thread per output pixel; loops 32 objects
// with bbox rejection, exact zero-padded bilinear (align_corners) sampling.
__global__ __launch_bounds__(256) void composite_kernel(const float* __restrict__ dec,
                                                        const float* __restrict__ obj,
                                                        float* __restrict__ out) {
    const int pix = blockIdx.x * 256 + threadIdx.x;  // 0..173055
    const int b = blockIdx.y;
    const int h = pix / IMAGE_SIZE;
    const int w = pix - h * IMAGE_SIZE;

    __shared__ float sobj[32 * 8];
    for (int k = threadIdx.x; k < 32 * 8; k += 256) sobj[k] = obj[b * 32 * 8 + k];
    __syncthreads();

    const float u = fmaf((float)w, 2.0f / 415.0f, -1.0f);
    const float v = fmaf((float)h, 2.0f / 415.0f, -1.0f);

    float a0 = 0.0f, a1 = 0.0f, a2 = 0.0f;

    for (int n = 0; n < 32; ++n) {
        const float wgt = sobj[n * 8 + 4];
        if (wgt == 0.0f) continue;
        const float gx = (u - sobj[n * 8 + 0]) * sobj[n * 8 + 2];
        const float gy = (v - sobj[n * 8 + 1]) * sobj[n * 8 + 3];
        const float px = (gx + 1.0f) * (0.5f * (DECODED - 1));  // *31.5
        const float py = (gy + 1.0f) * (0.5f * (DECODED - 1));
        if (px <= -1.0f || px >= (float)DECODED || py <= -1.0f || py >= (float)DECODED)
            continue;  // all four corners invalid -> contributes 0

        const float x0f = floorf(px), y0f = floorf(py);
        const int x0 = (int)x0f, y0 = (int)y0f;
        const float wx1 = px - x0f, wx0 = 1.0f - wx1;
        const float wy1 = py - y0f, wy0 = 1.0f - wy1;

        const bool vx0 = (x0 >= 0) & (x0 <= DECODED - 1);
        const bool vx1 = (x0 + 1 >= 0) & (x0 + 1 <= DECODED - 1);
        const bool vy0 = (y0 >= 0) & (y0 <= DECODED - 1);
        const bool vy1 = (y0 + 1 >= 0) & (y0 + 1 <= DECODED - 1);

        const int xc0 = min(max(x0, 0), DECODED - 1);
        const int xc1 = min(max(x0 + 1, 0), DECODED - 1);
        const int yc0 = min(max(y0, 0), DECODED - 1);
        const int yc1 = min(max(y0 + 1, 0), DECODED - 1);

        const float w00 = wx0 * wy0 * (float)(vx0 && vy0);
        const float w10 = wx1 * wy0 * (float)(vx1 && vy0);
        const float w01 = wx0 * wy1 * (float)(vx0 && vy1);
        const float w11 = wx1 * wy1 * (float)(vx1 && vy1);

        const float* base = dec + (size_t)(b * 32 + n) * OUT2;
        const int i00 = yc0 * DECODED + xc0;
        const int i10 = yc0 * DECODED + xc1;
        const int i01 = yc1 * DECODED + xc0;
        const int i11 = yc1 * DECODED + xc1;

        {
            const float* p = base;  // channel 0
            float g = w00 * p[i00] + w10 * p[i10] + w01 * p[i01] + w11 * p[i11];
            a0 = fmaf(wgt, g, a0);
        }
        {
            const float* p = base + 4096;  // channel 1
            float g = w00 * p[i00] + w10 * p[i10] + w01 * p[i01] + w11 * p[i11];
            a1 = fmaf(wgt, g, a1);
        }
        {
            const float* p = base + 8192;  // channel 2
            float g = w00 * p[i00] + w10 * p[i10] + w01 * p[i01] + w11 * p[i11];
            a2 = fmaf(wgt, g, a2);
        }
    }

    out[((size_t)(b * 3 + 0) * IMAGE_SIZE + h) * IMAGE_SIZE + w] = a0;
    out[((size_t)(b * 3 + 1) * IMAGE_SIZE + h) * IMAGE_SIZE + w] = a1;
    out[((size_t)(b * 3 + 2) * IMAGE_SIZE + h) * IMAGE_SIZE + w] = a2;
}

extern "C" void kernel_launch(void* const* d_in, const int* in_sizes, int n_in,
                              void* d_out, int out_size, void* d_ws, size_t ws_size,
                              hipStream_t stream) {
    const float* z_where  = (const float*)d_in[0];   // [4,32,4]
    const int*   z_present = (const int*)d_in[1];    // [4,32,1]
    const float* z_what   = (const float*)d_in[2];   // [4,32,64]
    const float* z_depth  = (const float*)d_in[3];   // [4,32,1]
    const float* w1 = (const float*)d_in[4];         // [64,512]
    const float* b1 = (const float*)d_in[5];         // [512]
    const float* w2 = (const float*)d_in[6];         // [512,12288]
    const float* b2 = (const float*)d_in[7];         // [12288]
    float* out = (float*)d_out;                      // [4,3,416,416] f32

    char* ws = (char*)d_ws;
    float* dec = (float*)ws;                                   // 128*12288*4 = 6,291,456 B
    float* hid = (float*)(ws + 6291456);                       // 128*512*4   =   262,144 B
    float* obj = (float*)(ws + 6291456 + 262144);              // 128*8*4     =     4,096 B

    mlp1_kernel<<<M_OBJ, 512, 0, stream>>>(z_what, w1, b1, hid);
    wts_kernel<<<1, 128, 0, stream>>>(z_where, z_present, z_depth, obj);
    mlp2_kernel<<<dim3(48, 8), 256, 0, stream>>>(hid, w2, b2, dec);
    composite_kernel<<<dim3(NPIX / 256, 4), 256, 0, stream>>>(dec, obj, out);
}